// Round 6
// baseline (6334.032 us; speedup 1.0000x reference)
//
#include <hip/hip_runtime.h>

typedef _Float16 f16_t;
typedef _Float16 f16x4 __attribute__((ext_vector_type(4)));
typedef _Float16 f16x8 __attribute__((ext_vector_type(8)));
typedef float floatx4 __attribute__((ext_vector_type(4)));

#define GLDS16(gptr, lptr) __builtin_amdgcn_global_load_lds( \
    (const __attribute__((address_space(1))) void*)(gptr),   \
    (__attribute__((address_space(3))) void*)(lptr), 16, 0, 0)

__device__ __forceinline__ float sigmoidf_fast(float x) {
    return 1.f / (1.f + __expf(-x));
}
__device__ __forceinline__ float tanhf_fast(float x) {
    float e = __expf(2.f * x);
    return 1.f - 2.f / (e + 1.f);
}

// gi fragment layout: off = ((g*512 + tM)*128 + tN)*256 + lane*4 + r   (f16)
#define GATE_STRIDE 16777216L   // 512*128*256

// ---------------------------------------------------------------------------
__global__ __launch_bounds__(256)
void cvt_f32_f16(const float* __restrict__ in, f16_t* __restrict__ out, long n)
{
    long i = ((long)blockIdx.x * 256 + threadIdx.x) * 8;
    if (i >= n) return;
    floatx4 a = *(const floatx4*)(in + i);
    floatx4 b = *(const floatx4*)(in + i + 4);
    f16x8 o;
    o[0] = (f16_t)a[0]; o[1] = (f16_t)a[1]; o[2] = (f16_t)a[2]; o[3] = (f16_t)a[3];
    o[4] = (f16_t)b[0]; o[5] = (f16_t)b[1]; o[6] = (f16_t)b[2]; o[7] = (f16_t)b[3];
    *(f16x8*)(out + i) = o;
}

// ---------------------------------------------------------------------------
// BK=64 staging (R3-proven): A-tile 128x64 (16 chunks of 8 rows x 64 f16),
// W-tile 3x64x64 (24 chunks), 1 KiB chunks, 8-slot XOR swizzle baked into
// the per-lane GLOBAL address (LDS dest stays linear).
// ---------------------------------------------------------------------------
__device__ __forceinline__ void stage_AW(const f16_t* __restrict__ Asrc,
                                         const f16_t* __restrict__ Wsrc,
                                         f16_t* Asb, f16_t* Wsb,
                                         int m0, int n0, int kk,
                                         int wave, int srow8, int sgk)
{
    const int K = 2048, H = 2048;
    #pragma unroll
    for (int j = 0; j < 4; ++j) {
        int c = j * 4 + wave;
        int row = c * 8 + srow8;
        GLDS16(Asrc + (size_t)(m0 + row) * K + kk + sgk, Asb + c * 512);
    }
    #pragma unroll
    for (int j = 0; j < 6; ++j) {
        int c = j * 4 + wave;
        int g = c >> 3;
        int cw = c & 7;
        int row = cw * 8 + srow8;
        GLDS16(Wsrc + (size_t)(g * H + n0 + row) * K + kk + sgk,
               Wsb + c * 512);
    }
}

// ---------------------------------------------------------------------------
// BK=32 staging (R6): A-tile 128x32 (8 chunks of 16 rows x 32 f16),
// W-tile 3x64x32 (12 chunks). 64 B rows, 4-slot XOR swizzle (slot s of row r
// holds k-chunk s ^ ((r>>1)&3)) — the R1-gemm_gi proven layout.
// ---------------------------------------------------------------------------
__device__ __forceinline__ void stage_AW32(const f16_t* __restrict__ Asrc,
                                           const f16_t* __restrict__ Wsrc,
                                           f16_t* Asb, f16_t* Wsb,
                                           int m0, int n0, int kk,
                                           int wave, int srow, int skc)
{
    const int K = 2048, H = 2048;
    // A: 8 chunks (16 rows x 32 f16 each), 2/wave
    #pragma unroll
    for (int j = 0; j < 2; ++j) {
        int c = j * 4 + wave;
        int row = c * 16 + srow;
        GLDS16(Asrc + (size_t)(m0 + row) * K + kk + skc, Asb + c * 512);
    }
    // W: 12 chunks (3 gates x 4), 3/wave
    #pragma unroll
    for (int j = 0; j < 3; ++j) {
        int c = j * 4 + wave;
        int g = c >> 2;
        int cw = c & 3;
        int row = cw * 16 + srow;
        GLDS16(Wsrc + (size_t)(g * H + n0 + row) * K + kk + skc,
               Wsb + c * 512);
    }
}

// ---------------------------------------------------------------------------
// gi = encoded @ w_ih^T + b_ih. R3-PROVEN version, unchanged: BM=128,
// BN=64x3 gates, BK=64, 2-phase dbuf (80 KiB, 2 blocks/CU), stage t+1
// before compute of t, one __syncthreads per K-step, XCD-swizzled grid.
// Serves as the in-round A/B reference against gru_step's BK=32 variant.
// ---------------------------------------------------------------------------
__global__ __launch_bounds__(256, 2)
void gemm_gi(const f16_t* __restrict__ A,
             const f16_t* __restrict__ W,
             const float* __restrict__ bias,
             f16_t* __restrict__ giF)
{
    const int H = 2048;
    __shared__ __align__(16) f16_t smem[2 * 20480];  // 80 KiB
    const int tid  = threadIdx.x;
    const int lane = tid & 63;
    const int wave = tid >> 6;

    const int bid   = blockIdx.x;
    const int xcd   = bid & 7;
    const int rblk  = bid >> 3;           // 0..255
    const int m0 = (rblk >> 2) * 128;     // 64 m-tiles
    const int n0 = (xcd * 4 + (rblk & 3)) * 64;   // 32 n-tiles (per gate)

    const int wm = (wave >> 1) * 64;
    const int wn = (wave & 1) * 32;

    floatx4 acc[3][4][2] = {};

    const int srow8 = lane >> 3;
    const int sgk   = ((lane & 7) ^ srow8) * 8;
    const int fr = lane & 15;
    const int jq = lane >> 4;
    const int rq = (lane >> 4) * 4;

    stage_AW(A, W, smem, smem + 8192, m0, n0, 0, wave, srow8, sgk);
    __syncthreads();

    for (int t = 0; t < 32; ++t) {
        f16_t* As  = smem + (t & 1) * 20480;
        f16_t* Wsm = As + 8192;
        if (t < 31) {
            f16_t* Asn = smem + ((t + 1) & 1) * 20480;
            stage_AW(A, W, Asn, Asn + 8192, m0, n0, (t + 1) * 64,
                     wave, srow8, sgk);
        }

        #pragma unroll
        for (int ksub = 0; ksub < 2; ++ksub) {
            f16x8 a_frag[4];
            #pragma unroll
            for (int u = 0; u < 4; ++u) {
                int row = wm + u * 16 + fr;
                int slot = (ksub * 4 + jq) ^ (row & 7);
                a_frag[u] = *(const f16x8*)(As + row * 64 + slot * 8);
            }
            #pragma unroll
            for (int g = 0; g < 3; ++g) {
                #pragma unroll
                for (int tn = 0; tn < 2; ++tn) {
                    int row_w = wn + tn * 16 + fr;
                    int slot = (ksub * 4 + jq) ^ (row_w & 7);
                    f16x8 b_frag = *(const f16x8*)(Wsm + g * 4096 +
                                                   row_w * 64 + slot * 8);
                    #pragma unroll
                    for (int tm = 0; tm < 4; ++tm)
                        acc[g][tm][tn] = __builtin_amdgcn_mfma_f32_16x16x32_f16(
                            a_frag[tm], b_frag, acc[g][tm][tn], 0, 0, 0);
                }
            }
        }
        __syncthreads();
    }

    // epilogue: bias + fragment-tiled store (3 gates)
    #pragma unroll
    for (int tm = 0; tm < 4; ++tm) {
        int tM = (m0 + wm + tm * 16) >> 4;
        #pragma unroll
        for (int tn = 0; tn < 2; ++tn) {
            int tN = ((n0 + wn) >> 4) + tn;
            int n  = n0 + wn + tn * 16 + fr;
            #pragma unroll
            for (int g = 0; g < 3; ++g) {
                float b = bias[g * H + n];
                f16x4 v;
                #pragma unroll
                for (int r = 0; r < 4; ++r) v[r] = (f16_t)(acc[g][tm][tn][r] + b);
                *(f16x4*)(giF + ((size_t)(g * 512 + tM) * 128 + tN) * 256 +
                          lane * 4) = v;
            }
        }
    }
}

// ---------------------------------------------------------------------------
// Iteration 1 (h0=0): gh = b_hh only.
// ---------------------------------------------------------------------------
__global__ __launch_bounds__(256)
void gru_init(const f16_t* __restrict__ giF,
              const float* __restrict__ bhh,
              f16_t* __restrict__ h16)
{
    const int H = 2048;
    __shared__ __align__(16) f16_t hp[128 * 72];
    const int tid  = threadIdx.x;
    const int lane = tid & 63;
    const int wave = tid >> 6;
    const int m0 = blockIdx.x * 128;
    const int n0 = blockIdx.y * 64;
    const int wm = (wave >> 1) * 64;
    const int wn = (wave & 1) * 32;
    const int colL = lane & 15;
    const int rq = (lane >> 4) * 4;

    #pragma unroll
    for (int tm = 0; tm < 4; ++tm) {
        int tM = (m0 + wm + tm * 16) >> 4;
        #pragma unroll
        for (int tn = 0; tn < 2; ++tn) {
            int tN = ((n0 + wn) >> 4) + tn;
            size_t base = ((size_t)tM * 128 + tN) * 256 + lane * 4;
            f16x4 g_r = *(const f16x4*)(giF + base);
            f16x4 g_z = *(const f16x4*)(giF + base + GATE_STRIDE);
            f16x4 g_n = *(const f16x4*)(giF + base + 2 * GATE_STRIDE);
            int n = n0 + wn + tn * 16 + colL;
            float br = bhh[n], bz = bhh[H + n], bn = bhh[2 * H + n];
            #pragma unroll
            for (int r = 0; r < 4; ++r) {
                float rr = sigmoidf_fast((float)g_r[r] + br);
                float zz = sigmoidf_fast((float)g_z[r] + bz);
                float nn = tanhf_fast((float)g_n[r] + rr * bn);
                float h = (1.f - zz) * nn;
                hp[(wm + tm * 16 + rq + r) * 72 + wn + tn * 16 + colL] = (f16_t)h;
            }
        }
    }
    __syncthreads();
    #pragma unroll
    for (int i = 0; i < 4; ++i) {
        int r2 = i * 32 + (tid >> 3);
        int ch = tid & 7;
        f16x8 v = *(const f16x8*)(hp + r2 * 72 + ch * 8);
        *(f16x8*)(h16 + (size_t)(m0 + r2) * H + n0 + ch * 8) = v;
    }
}

// ---------------------------------------------------------------------------
// Fused gh-GEMM (3 gates) + GRU update. BM=128, BN=64, BK=32 (R6).
// Same proven 2-phase dbuf scheme as R3 (stage t+1 before compute of t, one
// __syncthreads per K-step), but 20 KiB/buffer -> 40 KiB total ->
// 4 blocks/CU (16 waves, 4/SIMD). R3 evidence: LDS only ~57 B/cyc/CU of
// ~85-128 achievable -> not LDS-bound; 2 waves/SIMD issue/latency coverage
// is the limit. More resident blocks anti-phase the barriers.
// hold(h_prev) captured from the As tile at k0 == n0 + wn (the 64-wide col
// window now spans two BK=32 tiles; wn selects which). DO NOT cap VGPR
// below ~128 (R5: (256,3)-induced spill => WRITE_SIZE x4.4, dur x1.77).
// ---------------------------------------------------------------------------
__global__ __launch_bounds__(256, 4)
void gru_step(const f16_t* __restrict__ Wh,
              const float* __restrict__ bhh,
              const f16_t* __restrict__ giF,
              const f16_t* __restrict__ hin,
              f16_t* __restrict__ hout,
              float* __restrict__ out32)
{
    const int H = 2048;
    // per-buffer: As 128x32 (4096 f16) + Wsm 3x64x32 (6144 f16) = 20 KiB
    __shared__ __align__(16) f16_t smem[2 * 10240];  // 40 KiB
    const int tid  = threadIdx.x;
    const int lane = tid & 63;
    const int wave = tid >> 6;

    const int bid   = blockIdx.x;
    const int xcd   = bid & 7;
    const int rblk  = bid >> 3;           // 0..255
    const int m0 = (rblk >> 2) * 128;     // 64 m-tiles
    const int n0 = (xcd * 4 + (rblk & 3)) * 64;   // 32 n-tiles

    const int wm = (wave >> 1) * 64;
    const int wn = (wave & 1) * 32;

    floatx4 acc[3][4][2] = {};

    // BK=32 staging: chunk = 16 rows x 32 f16; 4 lanes/row, 4 slots of 16 B
    const int srow = lane >> 2;                         // 0..15
    const int skc  = ((lane & 3) ^ ((srow >> 1) & 3)) * 8;
    const int fr = lane & 15;
    const int jq = lane >> 4;
    const int jsw = (jq ^ ((fr >> 1) & 3)) * 8;         // read-side slot
    const int rq = (lane >> 4) * 4;

    f16x4 hold16[4][2];   // h_prev captured from LDS

    stage_AW32(hin, Wh, smem, smem + 4096, m0, n0, 0, wave, srow, skc);
    __syncthreads();

    for (int t = 0; t < 64; ++t) {
        const int k0 = t * 32;
        f16_t* As  = smem + (t & 1) * 10240;
        f16_t* Wsm = As + 4096;
        if (t < 63) {
            f16_t* Asn = smem + ((t + 1) & 1) * 10240;
            stage_AW32(hin, Wh, Asn, Asn + 4096, m0, n0, k0 + 32,
                       wave, srow, skc);
        }

        if (k0 == n0 + wn) {   // wave-uniform, once: capture h_prev from As
            #pragma unroll
            for (int tm = 0; tm < 4; ++tm) {
                #pragma unroll
                for (int tn = 0; tn < 2; ++tn) {
                    #pragma unroll
                    for (int r = 0; r < 4; ++r) {
                        int row_a = wm + tm * 16 + rq + r;
                        int kl    = tn * 16 + fr;            // 0..31
                        int slot  = (kl >> 3) ^ ((row_a >> 1) & 3);
                        hold16[tm][tn][r] =
                            As[row_a * 32 + slot * 8 + (kl & 7)];
                    }
                }
            }
        }

        f16x8 a_frag[4];
        #pragma unroll
        for (int u = 0; u < 4; ++u) {
            int row = wm + u * 16 + fr;
            a_frag[u] = *(const f16x8*)(As + row * 32 + jsw);
        }
        #pragma unroll
        for (int g = 0; g < 3; ++g) {
            #pragma unroll
            for (int tn = 0; tn < 2; ++tn) {
                int row_w = wn + tn * 16 + fr;
                f16x8 b_frag = *(const f16x8*)(Wsm + g * 2048 +
                                               row_w * 32 + jsw);
                #pragma unroll
                for (int tm = 0; tm < 4; ++tm)
                    acc[g][tm][tn] = __builtin_amdgcn_mfma_f32_16x16x32_f16(
                        a_frag[tm], b_frag, acc[g][tm][tn], 0, 0, 0);
            }
        }
        __syncthreads();
    }

    // epilogue
    f16x4 hv[4][2];
    #pragma unroll
    for (int tm = 0; tm < 4; ++tm) {
        int tM = (m0 + wm + tm * 16) >> 4;
        #pragma unroll
        for (int tn = 0; tn < 2; ++tn) {
            int tN = ((n0 + wn) >> 4) + tn;
            size_t base = ((size_t)tM * 128 + tN) * 256 + lane * 4;
            f16x4 g_r = *(const f16x4*)(giF + base);
            f16x4 g_z = *(const f16x4*)(giF + base + GATE_STRIDE);
            f16x4 g_n = *(const f16x4*)(giF + base + 2 * GATE_STRIDE);
            int n = n0 + wn + tn * 16 + fr;
            float br = bhh[n], bz = bhh[H + n], bn = bhh[2 * H + n];
            #pragma unroll
            for (int r = 0; r < 4; ++r) {
                int m = m0 + wm + tm * 16 + rq + r;
                float rr = sigmoidf_fast((float)g_r[r] + acc[0][tm][tn][r] + br);
                float zz = sigmoidf_fast((float)g_z[r] + acc[1][tm][tn][r] + bz);
                float nn = tanhf_fast((float)g_n[r] +
                                      rr * (acc[2][tm][tn][r] + bn));
                float hold = (float)hold16[tm][tn][r];
                float hnew = (1.f - zz) * nn + zz * hold;
                hv[tm][tn][r] = (f16_t)hnew;
                if (out32) out32[(size_t)m * H + n] = hnew;
            }
        }
    }

    if (!out32) {
        f16_t* hp = smem;   // 18 KiB <= 40 KiB; guarded by the loop's final
                            // __syncthreads (all waves past their LDS reads)
        #pragma unroll
        for (int tm = 0; tm < 4; ++tm)
            #pragma unroll
            for (int tn = 0; tn < 2; ++tn)
                #pragma unroll
                for (int r = 0; r < 4; ++r)
                    hp[(wm + tm * 16 + rq + r) * 72 + wn + tn * 16 + fr] =
                        hv[tm][tn][r];
        __syncthreads();
        #pragma unroll
        for (int i = 0; i < 4; ++i) {
            int r2 = i * 32 + (tid >> 3);
            int ch = tid & 7;
            f16x8 v = *(const f16x8*)(hp + r2 * 72 + ch * 8);
            *(f16x8*)(hout + (size_t)(m0 + r2) * H + n0 + ch * 8) = v;
        }
    }
}

extern "C" void kernel_launch(void* const* d_in, const int* in_sizes, int n_in,
                              void* d_out, int out_size, void* d_ws, size_t ws_size,
                              hipStream_t stream) {
    const float* x    = (const float*)d_in[0];
    const float* w_ih = (const float*)d_in[1];
    const float* w_hh = (const float*)d_in[2];
    const float* b_ih = (const float*)d_in[3];
    const float* b_hh = (const float*)d_in[4];
    float* out = (float*)d_out;

    char* ws = (char*)d_ws;
    f16_t* xh    = (f16_t*)(ws);
    f16_t* wih_h = (f16_t*)(ws + 33554432);
    f16_t* whh_h = (f16_t*)(ws + 33554432 + 25165824);
    f16_t* gi    = (f16_t*)(ws + 33554432 + 2 * 25165824);
    f16_t* h16a  = (f16_t*)(ws + 33554432 + 2 * 25165824 + 100663296);
    f16_t* h16b  = (f16_t*)(ws + 33554432 + 2 * 25165824 + 100663296 + 33554432);

    cvt_f32_f16<<<dim3(8192), 256, 0, stream>>>(x, xh, 16777216L);
    cvt_f32_f16<<<dim3(6144), 256, 0, stream>>>(w_ih, wih_h, 12582912L);
    cvt_f32_f16<<<dim3(6144), 256, 0, stream>>>(w_hh, whh_h, 12582912L);

    gemm_gi<<<dim3(2048), 256, 0, stream>>>(xh, wih_h, b_ih, gi);
    gru_init<<<dim3(64, 32), 256, 0, stream>>>(gi, b_hh, h16a);

    f16_t* hin = h16a; f16_t* hout = h16b;
    for (int it = 2; it <= 10; ++it) {
        float* o32 = (it == 10) ? out : nullptr;
        gru_step<<<dim3(2048), 256, 0, stream>>>(whh_h, b_hh, gi,
                                                 hin, hout, o32);
        f16_t* t = hin; hin = hout; hout = t;
    }
}

// Round 7
// 2546.829 us; speedup vs baseline: 2.4870x; 2.4870x over previous
//
#include <hip/hip_runtime.h>

typedef _Float16 f16_t;
typedef _Float16 f16x4 __attribute__((ext_vector_type(4)));
typedef _Float16 f16x8 __attribute__((ext_vector_type(8)));
typedef float floatx4 __attribute__((ext_vector_type(4)));

#define GLDS16(gptr, lptr) __builtin_amdgcn_global_load_lds( \
    (const __attribute__((address_space(1))) void*)(gptr),   \
    (__attribute__((address_space(3))) void*)(lptr), 16, 0, 0)

__device__ __forceinline__ float sigmoidf_fast(float x) {
    return 1.f / (1.f + __expf(-x));
}
__device__ __forceinline__ float tanhf_fast(float x) {
    float e = __expf(2.f * x);
    return 1.f - 2.f / (e + 1.f);
}

// gi fragment layout: off = ((g*512 + tM)*128 + tN)*256 + lane*4 + r   (f16)
#define GATE_STRIDE 16777216L   // 512*128*256

// ---------------------------------------------------------------------------
__global__ __launch_bounds__(256)
void cvt_f32_f16(const float* __restrict__ in, f16_t* __restrict__ out, long n)
{
    long i = ((long)blockIdx.x * 256 + threadIdx.x) * 8;
    if (i >= n) return;
    floatx4 a = *(const floatx4*)(in + i);
    floatx4 b = *(const floatx4*)(in + i + 4);
    f16x8 o;
    o[0] = (f16_t)a[0]; o[1] = (f16_t)a[1]; o[2] = (f16_t)a[2]; o[3] = (f16_t)a[3];
    o[4] = (f16_t)b[0]; o[5] = (f16_t)b[1]; o[6] = (f16_t)b[2]; o[7] = (f16_t)b[3];
    *(f16x8*)(out + i) = o;
}

// ---------------------------------------------------------------------------
// BK=64 staging (R3-proven, used by gemm_gi): A-tile 128x64 (16 chunks of
// 8 rows x 64 f16), W-tile 3x64x64 (24 chunks), 8-slot XOR swizzle baked
// into the per-lane GLOBAL address (LDS dest stays linear).
// ---------------------------------------------------------------------------
__device__ __forceinline__ void stage_AW(const f16_t* __restrict__ Asrc,
                                         const f16_t* __restrict__ Wsrc,
                                         f16_t* Asb, f16_t* Wsb,
                                         int m0, int n0, int kk,
                                         int wave, int srow8, int sgk)
{
    const int K = 2048, H = 2048;
    #pragma unroll
    for (int j = 0; j < 4; ++j) {
        int c = j * 4 + wave;
        int row = c * 8 + srow8;
        GLDS16(Asrc + (size_t)(m0 + row) * K + kk + sgk, Asb + c * 512);
    }
    #pragma unroll
    for (int j = 0; j < 6; ++j) {
        int c = j * 4 + wave;
        int g = c >> 3;
        int cw = c & 7;
        int row = cw * 8 + srow8;
        GLDS16(Wsrc + (size_t)(g * H + n0 + row) * K + kk + sgk,
               Wsb + c * 512);
    }
}

// ---------------------------------------------------------------------------
// BK=32 staging (R6-verified layout): A-tile 128x32 (8 chunks of 16 rows x
// 32 f16), W-tile 3x64x32 (12 chunks). 64 B rows, 4-slot XOR swizzle
// (slot s of row r holds k-chunk s ^ ((r>>1)&3)). 5 glds/thread.
// ---------------------------------------------------------------------------
__device__ __forceinline__ void stage_AW32(const f16_t* __restrict__ Asrc,
                                           const f16_t* __restrict__ Wsrc,
                                           f16_t* Asb, f16_t* Wsb,
                                           int m0, int n0, int kk,
                                           int wave, int srow, int skc)
{
    const int K = 2048, H = 2048;
    #pragma unroll
    for (int j = 0; j < 2; ++j) {
        int c = j * 4 + wave;
        int row = c * 16 + srow;
        GLDS16(Asrc + (size_t)(m0 + row) * K + kk + skc, Asb + c * 512);
    }
    #pragma unroll
    for (int j = 0; j < 3; ++j) {
        int c = j * 4 + wave;
        int g = c >> 2;
        int cw = c & 3;
        int row = cw * 16 + srow;
        GLDS16(Wsrc + (size_t)(g * H + n0 + row) * K + kk + skc,
               Wsb + c * 512);
    }
}

// ---------------------------------------------------------------------------
// gi = encoded @ w_ih^T + b_ih. R3-PROVEN, UNCHANGED (in-round A/B control):
// BM=128, BN=64x3 gates, BK=64, 2-phase dbuf (80 KiB, 2 blocks/CU),
// stage t+1 before compute of t, one __syncthreads per K-step, XCD swizzle.
// ---------------------------------------------------------------------------
__global__ __launch_bounds__(256, 2)
void gemm_gi(const f16_t* __restrict__ A,
             const f16_t* __restrict__ W,
             const float* __restrict__ bias,
             f16_t* __restrict__ giF)
{
    const int H = 2048;
    __shared__ __align__(16) f16_t smem[2 * 20480];  // 80 KiB
    const int tid  = threadIdx.x;
    const int lane = tid & 63;
    const int wave = tid >> 6;

    const int bid   = blockIdx.x;
    const int xcd   = bid & 7;
    const int rblk  = bid >> 3;           // 0..255
    const int m0 = (rblk >> 2) * 128;     // 64 m-tiles
    const int n0 = (xcd * 4 + (rblk & 3)) * 64;   // 32 n-tiles (per gate)

    const int wm = (wave >> 1) * 64;
    const int wn = (wave & 1) * 32;

    floatx4 acc[3][4][2] = {};

    const int srow8 = lane >> 3;
    const int sgk   = ((lane & 7) ^ srow8) * 8;
    const int fr = lane & 15;
    const int jq = lane >> 4;
    const int rq = (lane >> 4) * 4;

    stage_AW(A, W, smem, smem + 8192, m0, n0, 0, wave, srow8, sgk);
    __syncthreads();

    for (int t = 0; t < 32; ++t) {
        f16_t* As  = smem + (t & 1) * 20480;
        f16_t* Wsm = As + 8192;
        if (t < 31) {
            f16_t* Asn = smem + ((t + 1) & 1) * 20480;
            stage_AW(A, W, Asn, Asn + 8192, m0, n0, (t + 1) * 64,
                     wave, srow8, sgk);
        }

        #pragma unroll
        for (int ksub = 0; ksub < 2; ++ksub) {
            f16x8 a_frag[4];
            #pragma unroll
            for (int u = 0; u < 4; ++u) {
                int row = wm + u * 16 + fr;
                int slot = (ksub * 4 + jq) ^ (row & 7);
                a_frag[u] = *(const f16x8*)(As + row * 64 + slot * 8);
            }
            #pragma unroll
            for (int g = 0; g < 3; ++g) {
                #pragma unroll
                for (int tn = 0; tn < 2; ++tn) {
                    int row_w = wn + tn * 16 + fr;
                    int slot = (ksub * 4 + jq) ^ (row_w & 7);
                    f16x8 b_frag = *(const f16x8*)(Wsm + g * 4096 +
                                                   row_w * 64 + slot * 8);
                    #pragma unroll
                    for (int tm = 0; tm < 4; ++tm)
                        acc[g][tm][tn] = __builtin_amdgcn_mfma_f32_16x16x32_f16(
                            a_frag[tm], b_frag, acc[g][tm][tn], 0, 0, 0);
                }
            }
        }
        __syncthreads();
    }

    // epilogue: bias + fragment-tiled store (3 gates)
    #pragma unroll
    for (int tm = 0; tm < 4; ++tm) {
        int tM = (m0 + wm + tm * 16) >> 4;
        #pragma unroll
        for (int tn = 0; tn < 2; ++tn) {
            int tN = ((n0 + wn) >> 4) + tn;
            int n  = n0 + wn + tn * 16 + fr;
            #pragma unroll
            for (int g = 0; g < 3; ++g) {
                float b = bias[g * H + n];
                f16x4 v;
                #pragma unroll
                for (int r = 0; r < 4; ++r) v[r] = (f16_t)(acc[g][tm][tn][r] + b);
                *(f16x4*)(giF + ((size_t)(g * 512 + tM) * 128 + tN) * 256 +
                          lane * 4) = v;
            }
        }
    }
}

// ---------------------------------------------------------------------------
// Iteration 1 (h0=0): gh = b_hh only.
// ---------------------------------------------------------------------------
__global__ __launch_bounds__(256)
void gru_init(const f16_t* __restrict__ giF,
              const float* __restrict__ bhh,
              f16_t* __restrict__ h16)
{
    const int H = 2048;
    __shared__ __align__(16) f16_t hp[128 * 72];
    const int tid  = threadIdx.x;
    const int lane = tid & 63;
    const int wave = tid >> 6;
    const int m0 = blockIdx.x * 128;
    const int n0 = blockIdx.y * 64;
    const int wm = (wave >> 1) * 64;
    const int wn = (wave & 1) * 32;
    const int colL = lane & 15;
    const int rq = (lane >> 4) * 4;

    #pragma unroll
    for (int tm = 0; tm < 4; ++tm) {
        int tM = (m0 + wm + tm * 16) >> 4;
        #pragma unroll
        for (int tn = 0; tn < 2; ++tn) {
            int tN = ((n0 + wn) >> 4) + tn;
            size_t base = ((size_t)tM * 128 + tN) * 256 + lane * 4;
            f16x4 g_r = *(const f16x4*)(giF + base);
            f16x4 g_z = *(const f16x4*)(giF + base + GATE_STRIDE);
            f16x4 g_n = *(const f16x4*)(giF + base + 2 * GATE_STRIDE);
            int n = n0 + wn + tn * 16 + colL;
            float br = bhh[n], bz = bhh[H + n], bn = bhh[2 * H + n];
            #pragma unroll
            for (int r = 0; r < 4; ++r) {
                float rr = sigmoidf_fast((float)g_r[r] + br);
                float zz = sigmoidf_fast((float)g_z[r] + bz);
                float nn = tanhf_fast((float)g_n[r] + rr * bn);
                float h = (1.f - zz) * nn;
                hp[(wm + tm * 16 + rq + r) * 72 + wn + tn * 16 + colL] = (f16_t)h;
            }
        }
    }
    __syncthreads();
    #pragma unroll
    for (int i = 0; i < 4; ++i) {
        int r2 = i * 32 + (tid >> 3);
        int ch = tid & 7;
        f16x8 v = *(const f16x8*)(hp + r2 * 72 + ch * 8);
        *(f16x8*)(h16 + (size_t)(m0 + r2) * H + n0 + ch * 8) = v;
    }
}

// ---------------------------------------------------------------------------
// Fused gh-GEMM (3 gates) + GRU update. BM=128, BN=64, BK=32, TRIPLE buffer
// (R7). Rationale: with 2 buffers the end-of-iter wait is necessarily
// vmcnt(0) (newest loads are needed next); a 3rd buffer gives tile t+2's
// loads two full compute phases of cover and makes the wait a COUNTED
// s_waitcnt vmcnt(5) — 5 loads stay in flight across the barrier (T4).
// LDS 3 x 20 KiB = 60 KiB -> still 2 blocks/CU. launch_bounds (256,2) is
// the ONLY non-spilling config: effective VGPR cap = 512/(2*arg)
// (R3: (256,2)->120 ok; R5: (256,3)->84 spill; R6: (256,4)->64 spill).
// BK=32 tile layout + hold-capture verified correct in R6 (passed).
// ---------------------------------------------------------------------------
__global__ __launch_bounds__(256, 2)
void gru_step(const f16_t* __restrict__ Wh,
              const float* __restrict__ bhh,
              const f16_t* __restrict__ giF,
              const f16_t* __restrict__ hin,
              f16_t* __restrict__ hout,
              float* __restrict__ out32)
{
    const int H = 2048;
    // per-buffer: As 128x32 (4096 f16) + Wsm 3x64x32 (6144 f16) = 20 KiB
    __shared__ __align__(16) f16_t smem[3 * 10240];  // 60 KiB
    const int tid  = threadIdx.x;
    const int lane = tid & 63;
    const int wave = tid >> 6;

    const int bid   = blockIdx.x;
    const int xcd   = bid & 7;
    const int rblk  = bid >> 3;           // 0..255
    const int m0 = (rblk >> 2) * 128;     // 64 m-tiles
    const int n0 = (xcd * 4 + (rblk & 3)) * 64;   // 32 n-tiles

    const int wm = (wave >> 1) * 64;
    const int wn = (wave & 1) * 32;

    floatx4 acc[3][4][2] = {};

    // BK=32 staging: chunk = 16 rows x 32 f16; 4 lanes/row, 4 slots of 16 B
    const int srow = lane >> 2;                         // 0..15
    const int skc  = ((lane & 3) ^ ((srow >> 1) & 3)) * 8;
    const int fr = lane & 15;
    const int jq = lane >> 4;
    const int jsw = (jq ^ ((fr >> 1) & 3)) * 8;         // read-side slot
    const int rq = (lane >> 4) * 4;

    f16x4 hold16[4][2];   // h_prev captured from LDS

    f16_t* bufA = smem;            // tile t      (compute)
    f16_t* bufB = smem + 10240;    // tile t+1    (landed / in flight)
    f16_t* bufC = smem + 20480;    // tile t+2    (staging target)

    // prologue: stage tiles 0 and 1; wait only for tile 0 (tile 1 in flight)
    stage_AW32(hin, Wh, bufA, bufA + 4096, m0, n0, 0,  wave, srow, skc);
    stage_AW32(hin, Wh, bufB, bufB + 4096, m0, n0, 32, wave, srow, skc);
    asm volatile("s_waitcnt vmcnt(5)" ::: "memory");
    __builtin_amdgcn_s_barrier();

    for (int t = 0; t < 64; ++t) {
        const int k0 = t * 32;
        f16_t* As  = bufA;
        f16_t* Wsm = bufA + 4096;
        if (t < 62)   // stage tile t+2 into bufC (freed by end-of-(t-1) bar)
            stage_AW32(hin, Wh, bufC, bufC + 4096, m0, n0, k0 + 64,
                       wave, srow, skc);

        if (k0 == n0 + wn) {   // wave-uniform, once: capture h_prev from As
            #pragma unroll
            for (int tm = 0; tm < 4; ++tm) {
                #pragma unroll
                for (int tn = 0; tn < 2; ++tn) {
                    #pragma unroll
                    for (int r = 0; r < 4; ++r) {
                        int row_a = wm + tm * 16 + rq + r;
                        int kl    = tn * 16 + fr;            // 0..31
                        int slot  = (kl >> 3) ^ ((row_a >> 1) & 3);
                        hold16[tm][tn][r] =
                            As[row_a * 32 + slot * 8 + (kl & 7)];
                    }
                }
            }
        }

        f16x8 a_frag[4];
        #pragma unroll
        for (int u = 0; u < 4; ++u) {
            int row = wm + u * 16 + fr;
            a_frag[u] = *(const f16x8*)(As + row * 32 + jsw);
        }
        #pragma unroll
        for (int g = 0; g < 3; ++g) {
            #pragma unroll
            for (int tn = 0; tn < 2; ++tn) {
                int row_w = wn + tn * 16 + fr;
                f16x8 b_frag = *(const f16x8*)(Wsm + g * 2048 +
                                               row_w * 32 + jsw);
                #pragma unroll
                for (int tm = 0; tm < 4; ++tm)
                    acc[g][tm][tn] = __builtin_amdgcn_mfma_f32_16x16x32_f16(
                        a_frag[tm], b_frag, acc[g][tm][tn], 0, 0, 0);
            }
        }

        if (t < 63) {
            // publish tile t+1: counted wait leaves tile t+2's 5 loads in
            // flight (t<62); lgkmcnt(0) orders our ds_reads before other
            // waves may overwrite this buffer after the barrier.
            if (t < 62)
                asm volatile("s_waitcnt vmcnt(5) lgkmcnt(0)" ::: "memory");
            else
                asm volatile("s_waitcnt vmcnt(0) lgkmcnt(0)" ::: "memory");
            __builtin_amdgcn_s_barrier();
        }
        f16_t* tmp = bufA; bufA = bufB; bufB = bufC; bufC = tmp;
    }

    // epilogue
    f16x4 hv[4][2];
    #pragma unroll
    for (int tm = 0; tm < 4; ++tm) {
        int tM = (m0 + wm + tm * 16) >> 4;
        #pragma unroll
        for (int tn = 0; tn < 2; ++tn) {
            int tN = ((n0 + wn) >> 4) + tn;
            size_t base = ((size_t)tM * 128 + tN) * 256 + lane * 4;
            f16x4 g_r = *(const f16x4*)(giF + base);
            f16x4 g_z = *(const f16x4*)(giF + base + GATE_STRIDE);
            f16x4 g_n = *(const f16x4*)(giF + base + 2 * GATE_STRIDE);
            int n = n0 + wn + tn * 16 + fr;
            float br = bhh[n], bz = bhh[H + n], bn = bhh[2 * H + n];
            #pragma unroll
            for (int r = 0; r < 4; ++r) {
                int m = m0 + wm + tm * 16 + rq + r;
                float rr = sigmoidf_fast((float)g_r[r] + acc[0][tm][tn][r] + br);
                float zz = sigmoidf_fast((float)g_z[r] + acc[1][tm][tn][r] + bz);
                float nn = tanhf_fast((float)g_n[r] +
                                      rr * (acc[2][tm][tn][r] + bn));
                float hold = (float)hold16[tm][tn][r];
                float hnew = (1.f - zz) * nn + zz * hold;
                hv[tm][tn][r] = (f16_t)hnew;
                if (out32) out32[(size_t)m * H + n] = hnew;
            }
        }
    }

    if (!out32) {
        // hp lives in physical buffer 1 (smem+10240): tile 63 is read from
        // physical buffer 0 (63%3==0), and buffer 1's tile 62 was finished
        // by the end-of-62 barrier -> no overlap with in-flight reads.
        f16_t* hp = smem + 10240;   // 18 KiB <= 20 KiB region
        #pragma unroll
        for (int tm = 0; tm < 4; ++tm)
            #pragma unroll
            for (int tn = 0; tn < 2; ++tn)
                #pragma unroll
                for (int r = 0; r < 4; ++r)
                    hp[(wm + tm * 16 + rq + r) * 72 + wn + tn * 16 + fr] =
                        hv[tm][tn][r];
        __syncthreads();
        #pragma unroll
        for (int i = 0; i < 4; ++i) {
            int r2 = i * 32 + (tid >> 3);
            int ch = tid & 7;
            f16x8 v = *(const f16x8*)(hp + r2 * 72 + ch * 8);
            *(f16x8*)(hout + (size_t)(m0 + r2) * H + n0 + ch * 8) = v;
        }
    }
}

extern "C" void kernel_launch(void* const* d_in, const int* in_sizes, int n_in,
                              void* d_out, int out_size, void* d_ws, size_t ws_size,
                              hipStream_t stream) {
    const float* x    = (const float*)d_in[0];
    const float* w_ih = (const float*)d_in[1];
    const float* w_hh = (const float*)d_in[2];
    const float* b_ih = (const float*)d_in[3];
    const float* b_hh = (const float*)d_in[4];
    float* out = (float*)d_out;

    char* ws = (char*)d_ws;
    f16_t* xh    = (f16_t*)(ws);
    f16_t* wih_h = (f16_t*)(ws + 33554432);
    f16_t* whh_h = (f16_t*)(ws + 33554432 + 25165824);
    f16_t* gi    = (f16_t*)(ws + 33554432 + 2 * 25165824);
    f16_t* h16a  = (f16_t*)(ws + 33554432 + 2 * 25165824 + 100663296);
    f16_t* h16b  = (f16_t*)(ws + 33554432 + 2 * 25165824 + 100663296 + 33554432);

    cvt_f32_f16<<<dim3(8192), 256, 0, stream>>>(x, xh, 16777216L);
    cvt_f32_f16<<<dim3(6144), 256, 0, stream>>>(w_ih, wih_h, 12582912L);
    cvt_f32_f16<<<dim3(6144), 256, 0, stream>>>(w_hh, whh_h, 12582912L);

    gemm_gi<<<dim3(2048), 256, 0, stream>>>(xh, wih_h, b_ih, gi);
    gru_init<<<dim3(64, 32), 256, 0, stream>>>(gi, b_hh, h16a);

    f16_t* hin = h16a; f16_t* hout = h16b;
    for (int it = 2; it <= 10; ++it) {
        float* o32 = (it == 10) ? out : nullptr;
        gru_step<<<dim3(2048), 256, 0, stream>>>(whh_h, b_hh, gi,
                                                 hin, hout, o32);
        f16_t* t = hin; hin = hout; hout = t;
    }
}